// Round 1
// baseline (30293.936 us; speedup 1.0000x reference)
//
#include <hip/hip_runtime.h>
#include <hip/hip_bf16.h>

#define Bsz 128
#define Tt  512
#define Ff  64
#define Hh  512
#define G4  2048   // 4*H

// ws layout (float offsets)
#define OFF_H0   0
#define OFF_H1   (Bsz*Hh)                 // 65536
#define OFF_C    (2*Bsz*Hh)               // 131072
#define OFF_WEFF (3*Bsz*Hh)               // 196608
#define OFF_BEFF (OFF_WEFF + G4*Hh)       // 1245184
// total floats: 1247232  (~4.99 MB)

__device__ __forceinline__ float sigmoidf_(float x) {
    return 1.0f / (1.0f + expf(-x));
}

// W_eff = Wd_hh + Wd_ih @ Wo   [2048][512];  b_eff = bd + Wd_ih @ bo
__global__ __launch_bounds__(256) void prep_weff(
    const float* __restrict__ Wd_ih, const float* __restrict__ Wd_hh,
    const float* __restrict__ bd,    const float* __restrict__ Wo,
    const float* __restrict__ bo,    float* __restrict__ W_eff,
    float* __restrict__ b_eff)
{
    int idx = blockIdx.x * 256 + threadIdx.x;   // [0, 2048*512)
    int g = idx >> 9;          // row in [0,2048)
    int j = idx & 511;         // col in [0,512)
    float acc = Wd_hh[idx];
    const float* wi = Wd_ih + g * Ff;
    #pragma unroll 8
    for (int f = 0; f < Ff; ++f) acc += wi[f] * Wo[f * Hh + j];
    W_eff[idx] = acc;
    if (j == 0) {
        float bacc = bd[g];
        for (int f = 0; f < Ff; ++f) bacc += wi[f] * bo[f];
        b_eff[g] = bacc;
    }
}

// One LSTM step. Gate WGs (blockIdx < 256): each owns 2 h-cols (8 gate rows),
// computes gates for all 128 batches, updates c (in place) and h_out.
// Decoder also launches 8 extra WGs computing out_t = h_in@Wo.T + bo directly
// into d_out at the flipped time index.
template<int IS_DEC>
__global__ __launch_bounds__(256) void lstm_step(
    const float* __restrict__ h_in, float* __restrict__ h_out,
    float* __restrict__ c,
    const float* __restrict__ Wmain,   // [2048][512] We_hh or W_eff
    const float* __restrict__ Wx,      // [2048][64]  We_ih (enc only)
    const float* __restrict__ bias,    // [2048]
    const float* __restrict__ x_t,     // enc: ts + t*F (row stride T*F)
    const float* __restrict__ Wo,      // [64][512] (dec out WGs)
    const float* __restrict__ bo,      // [64]
    float* __restrict__ out_t)         // dec: d_out + (T-1-t)*F (row stride T*F)
{
    constexpr int K  = IS_DEC ? Hh : (Hh + Ff);   // 512 or 576
    constexpr int NT = K / 64;

    __shared__ __align__(16) float A_lds[Bsz * 68];   // [128][64] pad->68
    __shared__ __align__(16) float W_lds[8 * 580];    // [8][K<=576] pad->580

    const int w   = blockIdx.x;
    const int tid = threadIdx.x;
    const int b   = tid & 127;
    const int jj  = tid >> 7;          // 0/1 : which of the WG's 2 cols
    const bool is_out = (w >= 256);    // only reachable in decoder grid

    // ---- stage the 8 W rows for this WG into LDS (once) ----
    if (!is_out) {
        const int j0 = w << 1;
        for (int idx = tid; idx < 8 * K; idx += 256) {
            int r = idx / K, k = idx - r * K;
            int rj = r >> 2, rg = r & 3;
            int grow = rg * Hh + j0 + rj;     // gate-row in [0,2048)
            float v;
            if (IS_DEC) v = Wmain[grow * Hh + k];
            else        v = (k < Hh) ? Wmain[grow * Hh + k]
                                     : Wx[grow * Ff + (k - Hh)];
            W_lds[r * 580 + k] = v;
        }
    } else {
        const int f0 = (w - 256) << 3;
        for (int idx = tid; idx < 8 * K; idx += 256) {
            int r = idx / K, k = idx - r * K;
            W_lds[r * 580 + k] = Wo[(f0 + r) * Hh + k];
        }
    }

    float acc0 = 0.f, acc1 = 0.f, acc2 = 0.f, acc3 = 0.f;

    for (int kt = 0; kt < NT; ++kt) {
        __syncthreads();
        // ---- stage A tile [128 x 64] (h, then x for the encoder tail) ----
        const int base_k = kt * 64;
        #pragma unroll
        for (int i = 0; i < 8; ++i) {
            int idx4 = i * 256 + tid;       // float4 index
            int ab = idx4 >> 4;             // batch row
            int aq = idx4 & 15;             // float4 within row
            float4 v;
            if (IS_DEC || base_k < Hh) {
                v = *reinterpret_cast<const float4*>(
                        h_in + ab * Hh + base_k + aq * 4);
            } else {
                v = *reinterpret_cast<const float4*>(
                        x_t + (size_t)ab * (Tt * Ff) + (base_k - Hh) + aq * 4);
            }
            *reinterpret_cast<float4*>(&A_lds[ab * 68 + aq * 4]) = v;
        }
        __syncthreads();

        const float* Arow = &A_lds[b * 68];
        const float* W0 = &W_lds[(jj * 4 + 0) * 580 + base_k];
        const float* W1 = &W_lds[(jj * 4 + 1) * 580 + base_k];
        const float* W2 = &W_lds[(jj * 4 + 2) * 580 + base_k];
        const float* W3 = &W_lds[(jj * 4 + 3) * 580 + base_k];
        #pragma unroll
        for (int kk = 0; kk < 64; kk += 4) {
            float4 a  = *reinterpret_cast<const float4*>(Arow + kk);
            float4 w0 = *reinterpret_cast<const float4*>(W0 + kk);
            float4 w1 = *reinterpret_cast<const float4*>(W1 + kk);
            float4 w2 = *reinterpret_cast<const float4*>(W2 + kk);
            float4 w3 = *reinterpret_cast<const float4*>(W3 + kk);
            acc0 += a.x*w0.x + a.y*w0.y + a.z*w0.z + a.w*w0.w;
            acc1 += a.x*w1.x + a.y*w1.y + a.z*w1.z + a.w*w1.w;
            acc2 += a.x*w2.x + a.y*w2.y + a.z*w2.z + a.w*w2.w;
            acc3 += a.x*w3.x + a.y*w3.y + a.z*w3.z + a.w*w3.w;
        }
    }

    if (!is_out) {
        const int j  = (w << 1) + jj;
        const int ci = b * Hh + j;
        float gi = acc0 + bias[0 * Hh + j];
        float gf = acc1 + bias[1 * Hh + j];
        float gg = acc2 + bias[2 * Hh + j];
        float go = acc3 + bias[3 * Hh + j];
        float si = sigmoidf_(gi);
        float sf = sigmoidf_(gf);
        float tg = tanhf(gg);
        float so = sigmoidf_(go);
        float cn = sf * c[ci] + si * tg;
        c[ci] = cn;
        h_out[ci] = so * tanhf(cn);
    } else {
        const int fb = ((w - 256) << 3) + jj * 4;
        size_t ob = (size_t)b * (Tt * Ff) + fb;
        out_t[ob + 0] = acc0 + bo[fb + 0];
        out_t[ob + 1] = acc1 + bo[fb + 1];
        out_t[ob + 2] = acc2 + bo[fb + 2];
        out_t[ob + 3] = acc3 + bo[fb + 3];
    }
}

// h_lat = h_enc @ Wm.T + bm   (same staging structure, 2 rows per WG)
__global__ __launch_bounds__(256) void latent_kernel(
    const float* __restrict__ h_in, float* __restrict__ h_out,
    const float* __restrict__ Wm, const float* __restrict__ bm)
{
    __shared__ __align__(16) float A_lds[Bsz * 68];
    __shared__ __align__(16) float W_lds[2 * 580];
    const int w = blockIdx.x, tid = threadIdx.x;
    const int b = tid & 127, jj = tid >> 7;
    const int j0 = w << 1;

    for (int idx = tid; idx < 2 * Hh; idx += 256) {
        int r = idx >> 9, k = idx & 511;
        W_lds[r * 580 + k] = Wm[(j0 + r) * Hh + k];
    }

    float acc = 0.f;
    for (int kt = 0; kt < 8; ++kt) {
        __syncthreads();
        #pragma unroll
        for (int i = 0; i < 8; ++i) {
            int idx4 = i * 256 + tid;
            int ab = idx4 >> 4, aq = idx4 & 15;
            *reinterpret_cast<float4*>(&A_lds[ab * 68 + aq * 4]) =
                *reinterpret_cast<const float4*>(h_in + ab * Hh + kt * 64 + aq * 4);
        }
        __syncthreads();
        const float* Arow = &A_lds[b * 68];
        const float* Wr   = &W_lds[jj * 580 + kt * 64];
        #pragma unroll
        for (int kk = 0; kk < 64; kk += 4) {
            float4 a  = *reinterpret_cast<const float4*>(Arow + kk);
            float4 wv = *reinterpret_cast<const float4*>(Wr + kk);
            acc += a.x*wv.x + a.y*wv.y + a.z*wv.z + a.w*wv.w;
        }
    }
    int j = j0 + jj;
    h_out[b * Hh + j] = acc + bm[j];
}

extern "C" void kernel_launch(void* const* d_in, const int* in_sizes, int n_in,
                              void* d_out, int out_size, void* d_ws, size_t ws_size,
                              hipStream_t stream)
{
    const float* ts    = (const float*)d_in[0];
    const float* We_ih = (const float*)d_in[1];
    const float* We_hh = (const float*)d_in[2];
    const float* be    = (const float*)d_in[3];
    const float* Wd_ih = (const float*)d_in[4];
    const float* Wd_hh = (const float*)d_in[5];
    const float* bd    = (const float*)d_in[6];
    const float* Wm    = (const float*)d_in[7];
    const float* bm    = (const float*)d_in[8];
    const float* Wo    = (const float*)d_in[9];
    const float* bo    = (const float*)d_in[10];
    float* out = (float*)d_out;
    float* ws  = (float*)d_ws;

    float* h0    = ws + OFF_H0;
    float* h1    = ws + OFF_H1;
    float* c     = ws + OFF_C;
    float* W_eff = ws + OFF_WEFF;
    float* b_eff = ws + OFF_BEFF;

    // zero h0 / h1 / c (ws is poisoned 0xAA before every call)
    hipMemsetAsync(d_ws, 0, (size_t)(3 * Bsz * Hh) * sizeof(float), stream);

    prep_weff<<<G4 * Hh / 256, 256, 0, stream>>>(Wd_ih, Wd_hh, bd, Wo, bo,
                                                 W_eff, b_eff);

    // ---- encoder: 512 sequential steps, h ping-pong h0 -> h1 -> h0 ... ----
    for (int t = 0; t < Tt; ++t) {
        const float* hi = (t & 1) ? h1 : h0;
        float*       ho = (t & 1) ? h0 : h1;
        lstm_step<0><<<256, 256, 0, stream>>>(hi, ho, c, We_hh, We_ih, be,
                                              ts + t * Ff,
                                              nullptr, nullptr, nullptr);
    }
    // h_enc now in h0 (512 even), c_enc in c.

    // ---- latent mean: h_lat -> h1 ----
    latent_kernel<<<256, 256, 0, stream>>>(h0, h1, Wm, bm);

    // ---- decoder: 512 steps with folded weights; writes outs directly ----
    for (int k = 0; k < Tt; ++k) {
        const float* hi = (k & 1) ? h0 : h1;
        float*       ho = (k & 1) ? h1 : h0;
        lstm_step<1><<<264, 256, 0, stream>>>(hi, ho, c, W_eff, nullptr, b_eff,
                                              nullptr, Wo, bo,
                                              out + (size_t)(Tt - 1 - k) * Ff);
    }
}

// Round 5
// 2862.222 us; speedup vs baseline: 10.5841x; 10.5841x over previous
//
#include <hip/hip_runtime.h>
#include <hip/hip_fp16.h>

#define Bsz 128
#define Tt  512
#define Ff  64
#define Hh  512

typedef _Float16 half8 __attribute__((ext_vector_type(8)));
typedef float f32x4 __attribute__((ext_vector_type(4)));
typedef unsigned long long ull;
typedef unsigned short u16;

#define KPAD 648   // Wlds row stride (halves): 1296B = 324 dw, 324%32=4 -> 2-way (free)
#define APAD 520   // Alds row stride (halves): 1040B = 260 dw, 260%32=4 -> 2-way (free)

union HU { _Float16 h; u16 u; };

__device__ __forceinline__ float sigf(float x)     { return 1.0f / (1.0f + __expf(-x)); }
__device__ __forceinline__ float tanhfast(float x) { return 1.0f - 2.0f / (__expf(2.0f * x) + 1.0f); }

// W_eff = Wd_hh + Wd_ih @ Wo  (decoder feedback folded; out becomes pure side-output)
__global__ __launch_bounds__(256) void prep_weff(
    const float* __restrict__ Wd_ih, const float* __restrict__ Wd_hh,
    const float* __restrict__ bd,    const float* __restrict__ Wo,
    const float* __restrict__ bo,    _Float16* __restrict__ W16,
    float* __restrict__ beff)
{
    int idx = blockIdx.x * 256 + threadIdx.x;   // [0, 2048*512)
    int g = idx >> 9, j = idx & 511;
    float acc = Wd_hh[idx];
    const float* wi = Wd_ih + g * Ff;
    #pragma unroll 8
    for (int f = 0; f < Ff; ++f) acc += wi[f] * Wo[f * Hh + j];
    W16[idx] = (_Float16)acc;
    if (j == 0) {
        float b = bd[g];
        for (int f = 0; f < Ff; ++f) b += wi[f] * bo[f];
        beff[g] = b;
    }
}

// Persistent LSTM: 8 groups x 32 members. Group g: batches [16g,16g+16).
// Member m: h-cols [16m,16m+16) => 64 gate rows, weights resident in LDS fp16.
// Per wave w: MFMA tile rows = (jc_local*4+gamma), so lane (l) holds all 4 gates
// of (batch=l&15, jc=w*4+(l>>4)) in acc[0..3]; c lives in 1 VGPR all 1024 steps.
__global__ __launch_bounds__(256, 1) void lstm_persist(
    const float* __restrict__ ts,
    const float* __restrict__ We_ih, const float* __restrict__ We_hh,
    const float* __restrict__ be,
    const float* __restrict__ Wm,    const float* __restrict__ bm,
    const float* __restrict__ Wo,    const float* __restrict__ bo,
    const _Float16* __restrict__ Weff, const float* __restrict__ beff,
    _Float16* __restrict__ hbuf,   // [8][2][16][512] fp16 (device-scope exchanged)
    int* __restrict__ flags,       // [8][64] ints, memset 0 before launch
    float* __restrict__ out)
{
    __shared__ __align__(16) _Float16 Wlds[64 * KPAD];   // 82944 B  (>80KB => 1 WG/CU)
    __shared__ __align__(16) _Float16 Alds[16 * APAD];   // 16640 B

    const int bid = blockIdx.x;
    const int g = bid & 7, m = bid >> 3;   // bid%8 keeps a group on one XCD (perf only)
    const int tid = threadIdx.x;
    const int w = tid >> 6, l = tid & 63;
    const int bL = l & 15, kg = l >> 4;
    const int jj = m * 16 + w * 4 + kg;    // this lane's owned h-column
    const int gb0 = g * 16;

    _Float16* hb0 = hbuf + (size_t)(g * 2 + 0) * 16 * Hh;
    _Float16* hb1 = hbuf + (size_t)(g * 2 + 1) * 16 * Hh;
    int* gflags = flags + g * 64;

    int step = 1;

    auto gbar = [&]() {
        __syncthreads();  // compiler emits s_waitcnt vmcnt(0) before s_barrier:
                          // all this WG's device-scope h-stores are drained first
        if (tid == 0)
            __hip_atomic_store(&gflags[m], step, __ATOMIC_RELAXED, __HIP_MEMORY_SCOPE_AGENT);
        if (tid < 32) {
            while (__hip_atomic_load(&gflags[tid], __ATOMIC_RELAXED, __HIP_MEMORY_SCOPE_AGENT) < step)
                __builtin_amdgcn_s_sleep(1);
        }
        step++;
        __syncthreads();
    };

    // group h-tile (16KB = 2048 ull, 128 ull per batch row) -> LDS
    auto stageA = [&](const _Float16* cur) {
        const ull* src = (const ull*)cur;
        ull v[8];
        #pragma unroll
        for (int i = 0; i < 8; ++i)
            v[i] = __hip_atomic_load((ull*)(src + i * 256 + tid),
                                     __ATOMIC_RELAXED, __HIP_MEMORY_SCOPE_AGENT);
        #pragma unroll
        for (int i = 0; i < 8; ++i) {
            int idx = i * 256 + tid;
            int b_ = idx >> 7, q = idx & 127;      // 128 ull per 512-half row
            *(ull*)&Alds[b_ * APAD + q * 4] = v[i];
        }
    };

    // lane role (bL, jc=w*4+kg): gather 4 cols of same batch, store 8B
    auto packStore = [&](float hval, _Float16* nxt) {
        HU cv; cv.h = (_Float16)hval;
        int hv = (int)cv.u;
        int a0 = __shfl(hv, bL +  0, 64);
        int a1 = __shfl(hv, bL + 16, 64);
        int a2 = __shfl(hv, bL + 32, 64);
        int a3 = __shfl(hv, bL + 48, 64);
        if (l < 16) {
            ull packed = (ull)(unsigned)(a0 | (a1 << 16)) |
                         ((ull)(unsigned)(a2 | (a3 << 16)) << 32);
            __hip_atomic_store((ull*)&nxt[bL * Hh + m * 16 + w * 4], packed,
                               __ATOMIC_RELAXED, __HIP_MEMORY_SCOPE_AGENT);
        }
    };

    // ---- one-time: encoder weights -> LDS fp16 (rows R: jc=R>>2, gamma=R&3) ----
    for (int idx = tid; idx < 64 * 144; idx += 256) {
        int R = idx / 144, kq = idx - R * 144;
        int grow = (R & 3) * Hh + m * 16 + (R >> 2);
        float4 v;
        if (kq < 128) v = *(const float4*)(We_hh + (size_t)grow * Hh + kq * 4);
        else          v = *(const float4*)(We_ih + (size_t)grow * Ff + (kq - 128) * 4);
        _Float16* dst = &Wlds[R * KPAD + kq * 4];
        dst[0] = (_Float16)v.x; dst[1] = (_Float16)v.y;
        dst[2] = (_Float16)v.z; dst[3] = (_Float16)v.w;
    }
    if (tid < 64) {  // zero my slice of h state, buffer 0
        int b_ = tid >> 2, q = tid & 3;
        __hip_atomic_store((ull*)&hb0[b_ * Hh + m * 16 + q * 4], 0ull,
                           __ATOMIC_RELAXED, __HIP_MEMORY_SCOPE_AGENT);
    }
    float bias0 = be[0 * Hh + jj], bias1 = be[1 * Hh + jj],
          bias2 = be[2 * Hh + jj], bias3 = be[3 * Hh + jj];
    float c = 0.f;
    gbar();

    int par = 0;

    // =========================== encoder: 512 steps ===========================
    for (int t = 0; t < Tt; ++t) {
        const _Float16* cur = par ? hb1 : hb0;
        _Float16*       nxt = par ? hb0 : hb1;
        stageA(cur);
        __syncthreads();

        f32x4 acc0 = {0.f, 0.f, 0.f, 0.f}, acc1 = {0.f, 0.f, 0.f, 0.f};
        const _Float16* wrow = &Wlds[(w * 16 + bL) * KPAD + kg * 8];
        const _Float16* arow = &Alds[bL * APAD + kg * 8];
        #pragma unroll
        for (int kt = 0; kt < 16; ++kt) {
            half8 af = *(const half8*)(wrow + kt * 32);
            half8 bf = *(const half8*)(arow + kt * 32);
            if (kt & 1) acc1 = __builtin_amdgcn_mfma_f32_16x16x32_f16(af, bf, acc1, 0, 0, 0);
            else        acc0 = __builtin_amdgcn_mfma_f32_16x16x32_f16(af, bf, acc0, 0, 0, 0);
        }
        const float* xp = ts + ((size_t)(gb0 + bL) * Tt + t) * Ff + kg * 8;
        #pragma unroll
        for (int kt = 16; kt < 18; ++kt) {
            half8 af = *(const half8*)(wrow + kt * 32);
            float4 x0 = *(const float4*)(xp + (kt - 16) * 32);
            float4 x1 = *(const float4*)(xp + (kt - 16) * 32 + 4);
            half8 bf;
            bf[0]=(_Float16)x0.x; bf[1]=(_Float16)x0.y; bf[2]=(_Float16)x0.z; bf[3]=(_Float16)x0.w;
            bf[4]=(_Float16)x1.x; bf[5]=(_Float16)x1.y; bf[6]=(_Float16)x1.z; bf[7]=(_Float16)x1.w;
            if (kt & 1) acc1 = __builtin_amdgcn_mfma_f32_16x16x32_f16(af, bf, acc1, 0, 0, 0);
            else        acc0 = __builtin_amdgcn_mfma_f32_16x16x32_f16(af, bf, acc0, 0, 0, 0);
        }

        float gi = acc0[0] + acc1[0] + bias0;
        float gf = acc0[1] + acc1[1] + bias1;
        float gg = acc0[2] + acc1[2] + bias2;
        float go = acc0[3] + acc1[3] + bias3;
        c = sigf(gf) * c + sigf(gi) * tanhfast(gg);
        float h = sigf(go) * tanhfast(c);
        packStore(h, nxt);
        gbar();
        par ^= 1;
    }

    // ====================== latent + decoder weight swap ======================
    {
        const _Float16* he  = par ? hb1 : hb0;
        _Float16*       nxt = par ? hb0 : hb1;
        int b_ = tid & 15, jc2 = tid >> 4;       // jc2 == w*4+kg, b_ == bL
        int j2 = m * 16 + jc2;
        const float* wmr = Wm + (size_t)j2 * Hh;
        const ull* hrow = (const ull*)(he + b_ * Hh);
        float acc = bm[j2];
        #pragma unroll 4
        for (int q = 0; q < 128; ++q) {
            ull hv = __hip_atomic_load((ull*)(hrow + q),
                                       __ATOMIC_RELAXED, __HIP_MEMORY_SCOPE_AGENT);
            float4 wv = *(const float4*)(wmr + q * 4);
            HU e0, e1, e2, e3;
            e0.u = (u16)hv; e1.u = (u16)(hv >> 16);
            e2.u = (u16)(hv >> 32); e3.u = (u16)(hv >> 48);
            acc += (float)e0.h * wv.x + (float)e1.h * wv.y
                 + (float)e2.h * wv.z + (float)e3.h * wv.w;
        }
        // overlay decoder weights (enc Wlds last read before previous gbar)
        for (int idx = tid; idx < 64 * 64; idx += 256) {
            int R = idx >> 6, q8 = idx & 63;
            int grow = (R & 3) * Hh + m * 16 + (R >> 2);
            *(half8*)&Wlds[R * KPAD + q8 * 8] =
                *(const half8*)(Weff + (size_t)grow * Hh + q8 * 8);
        }
        bias0 = beff[0 * Hh + jj]; bias1 = beff[1 * Hh + jj];
        bias2 = beff[2 * Hh + jj]; bias3 = beff[3 * Hh + jj];
        packStore(acc, nxt);   // h_lat becomes decoder h-state (c carries in regs)
        gbar();
        par ^= 1;
    }

    // =========================== decoder: 512 steps ===========================
    for (int k = 0; k < Tt; ++k) {
        const _Float16* cur = par ? hb1 : hb0;
        _Float16*       nxt = par ? hb0 : hb1;
        stageA(cur);
        __syncthreads();

        // out[:, 511-k, :] = h @ Wo.T + bo   (32 (b,f) pairs, 8 lanes each)
        {
            int pr = w * 8 + (l >> 3);
            int ob = pr & 15, fs = pr >> 4;
            int chunk = l & 7;
            int f = 2 * m + fs;
            const float* wor = Wo + (size_t)f * Hh + chunk * 64;
            const _Float16* ha = &Alds[ob * APAD + chunk * 64];
            float oa = 0.f;
            #pragma unroll
            for (int q = 0; q < 8; ++q) {
                half8 hv = *(const half8*)(ha + q * 8);
                float4 w0 = *(const float4*)(wor + q * 8);
                float4 w1 = *(const float4*)(wor + q * 8 + 4);
                oa += (float)hv[0]*w0.x + (float)hv[1]*w0.y + (float)hv[2]*w0.z + (float)hv[3]*w0.w
                    + (float)hv[4]*w1.x + (float)hv[5]*w1.y + (float)hv[6]*w1.z + (float)hv[7]*w1.w;
            }
            oa += __shfl_xor(oa, 1, 64);
            oa += __shfl_xor(oa, 2, 64);
            oa += __shfl_xor(oa, 4, 64);
            if (chunk == 0)
                out[((size_t)(gb0 + ob) * Tt + (Tt - 1 - k)) * Ff + f] = oa + bo[f];
        }

        f32x4 acc0 = {0.f, 0.f, 0.f, 0.f}, acc1 = {0.f, 0.f, 0.f, 0.f};
        const _Float16* wrow = &Wlds[(w * 16 + bL) * KPAD + kg * 8];
        const _Float16* arow = &Alds[bL * APAD + kg * 8];
        #pragma unroll
        for (int kt = 0; kt < 16; ++kt) {
            half8 af = *(const half8*)(wrow + kt * 32);
            half8 bf = *(const half8*)(arow + kt * 32);
            if (kt & 1) acc1 = __builtin_amdgcn_mfma_f32_16x16x32_f16(af, bf, acc1, 0, 0, 0);
            else        acc0 = __builtin_amdgcn_mfma_f32_16x16x32_f16(af, bf, acc0, 0, 0, 0);
        }

        float gi = acc0[0] + acc1[0] + bias0;
        float gf = acc0[1] + acc1[1] + bias1;
        float gg = acc0[2] + acc1[2] + bias2;
        float go = acc0[3] + acc1[3] + bias3;
        c = sigf(gf) * c + sigf(gi) * tanhfast(gg);
        float h = sigf(go) * tanhfast(c);
        packStore(h, nxt);
        gbar();
        par ^= 1;
    }
}

extern "C" void kernel_launch(void* const* d_in, const int* in_sizes, int n_in,
                              void* d_out, int out_size, void* d_ws, size_t ws_size,
                              hipStream_t stream)
{
    (void)in_sizes; (void)n_in; (void)out_size; (void)ws_size;
    const float* ts    = (const float*)d_in[0];
    const float* We_ih = (const float*)d_in[1];
    const float* We_hh = (const float*)d_in[2];
    const float* be    = (const float*)d_in[3];
    const float* Wd_ih = (const float*)d_in[4];
    const float* Wd_hh = (const float*)d_in[5];
    const float* bd    = (const float*)d_in[6];
    const float* Wm    = (const float*)d_in[7];
    const float* bm    = (const float*)d_in[8];
    const float* Wo    = (const float*)d_in[9];
    const float* bo    = (const float*)d_in[10];

    char* ws = (char*)d_ws;
    int*      flags = (int*)(ws + 0);                        // 2048 B
    _Float16* hbuf  = (_Float16*)(ws + 2048);                // 262144 B
    _Float16* Weff  = (_Float16*)(ws + 2048 + 262144);       // 2097152 B
    float*    beff  = (float*)(ws + 2048 + 262144 + 2097152);// 8192 B

    hipMemsetAsync(flags, 0, 2048, stream);
    prep_weff<<<4096, 256, 0, stream>>>(Wd_ih, Wd_hh, bd, Wo, bo, Weff, beff);
    lstm_persist<<<256, 256, 0, stream>>>(ts, We_ih, We_hh, be, Wm, bm, Wo, bo,
                                          Weff, beff, hbuf, flags, (float*)d_out);
}